// Round 3
// baseline (557.354 us; speedup 1.0000x reference)
//
#include <hip/hip_runtime.h>

typedef unsigned short ushort_t;
typedef __attribute__((ext_vector_type(8))) short bf16x8;   // 8 bf16 in 4 VGPRs
typedef __attribute__((ext_vector_type(4))) float f32x4;

#define H 512
#define E 1024
#define S 2048
#define B 32

__device__ __forceinline__ ushort_t f2bf(float f) {
    unsigned u = __float_as_uint(f);
    unsigned r = (u + 0x7FFFu + ((u >> 16) & 1u)) >> 16;   // round-to-nearest-even
    return (ushort_t)r;
}

__device__ __forceinline__ uint4 pack8(float4 x, float4 y) {
    uint4 u;
    u.x = (unsigned)f2bf(x.x) | ((unsigned)f2bf(x.y) << 16);
    u.y = (unsigned)f2bf(x.z) | ((unsigned)f2bf(x.w) << 16);
    u.z = (unsigned)f2bf(y.x) | ((unsigned)f2bf(y.y) << 16);
    u.w = (unsigned)f2bf(y.z) | ((unsigned)f2bf(y.w) << 16);
    return u;
}

// hb[b][h] = hidden[b] @ Wh + ba  — split-K over 8 chunks, atomicAdd into zeroed hb
__global__ void prep_hb(const float* __restrict__ hidden, const float* __restrict__ Wa,
                        const float* __restrict__ ba, float* __restrict__ hb) {
    int b = blockIdx.x, kc = blockIdx.y, tid = threadIdx.x;
    const float* hp = hidden + b * H + kc * 64;
    float a0 = 0.f, a1 = 0.f;
    #pragma unroll 8
    for (int k = 0; k < 64; ++k) {
        float hv = hp[k];
        a0 += hv * Wa[(size_t)(kc * 64 + k) * H + tid];
        a1 += hv * Wa[(size_t)(kc * 64 + k) * H + tid + 256];
    }
    if (kc == 0) { a0 += ba[tid]; a1 += ba[tid + 256]; }
    atomicAdd(&hb[b * H + tid], a0);
    atomicAdd(&hb[b * H + tid + 256], a1);
}

// Swizzle We (= Wa[512:]) into bf16 MFMA-B-fragment order:
// wef[((kt*32+nt)*64 + lane)*8 + j] = We[kt*32 + (lane>>4)*8 + j][nt*16 + (lane&15)]
__global__ void prep_wef(const float* __restrict__ Wa, ushort_t* __restrict__ wef) {
    int g = blockIdx.x * 256 + threadIdx.x;      // 0..65535
    int kt = g >> 11, nt = (g >> 6) & 31, l = g & 63;
    int kbase = kt * 32 + ((l >> 4) << 3);
    int n = nt * 16 + (l & 15);
    #pragma unroll
    for (int j = 0; j < 8; ++j)
        wef[(size_t)g * 8 + j] = f2bf(Wa[(size_t)(H + kbase + j) * H + n]);
}

// Fused: scores[b][s] = v . tanh( enc[b,s,:] @ We + hb[b,:] )
// WG: 256 thr (4 waves), tile M=64 x N=512 (full), K in steps of 32 (one MFMA-K).
// B (wef, already fragment-ordered) staged global->LDS via global_load_lds,
// double-buffered; A converted fp32->bf16 through registers at distance 2.
__launch_bounds__(256, 2)
__global__ void score_kernel(const float* __restrict__ enc, const ushort_t* __restrict__ wef,
                             const float* __restrict__ hb, const float* __restrict__ v,
                             float* __restrict__ scores) {
    int b = blockIdx.y;
    int s0 = blockIdx.x * 64;
    int tid = threadIdx.x;
    int wave = tid >> 6, lane = tid & 63;
    int q = lane >> 4, nl = lane & 15;

    __shared__ ushort_t Bs[2][32 * 64 * 8];   // 2 x 32 KB, fragment order
    __shared__ ushort_t As[2][64 * 40];       // 2 x 5 KB, row pad 40 (80B, 16B-aligned)
    __shared__ float sred[4][64];

    f32x4 acc[4][8] = {};

    // A load mapping: row = tid>>2 (0..63), col0 = (tid&3)*8
    int arow = tid >> 2, acol = (tid & 3) * 8;
    const float* asrc = enc + ((size_t)b * S + s0 + arow) * E + acol;

    // B staging: wave w copies shorts [w*4096, w*4096+4096) of each 16384-short slice
    const ushort_t* bsrc = wef + (size_t)wave * 4096 + (size_t)lane * 8;

    float4 areg[2][2];
    areg[0][0] = *(const float4*)(asrc);
    areg[0][1] = *(const float4*)(asrc + 4);
    areg[1][0] = *(const float4*)(asrc + 32);
    areg[1][1] = *(const float4*)(asrc + 36);

    // stage B kt=0 -> Bs[0]
    #pragma unroll
    for (int j = 0; j < 8; ++j)
        __builtin_amdgcn_global_load_lds(
            (const __attribute__((address_space(1))) unsigned*)(bsrc + j * 512),
            (__attribute__((address_space(3))) unsigned*)(&Bs[0][wave * 4096 + j * 512]),
            16, 0, 0);

    // convert A kt=0 -> As[0]
    *(uint4*)&As[0][arow * 40 + acol] = pack8(areg[0][0], areg[0][1]);
    __syncthreads();

    for (int kt = 0; kt < 32; ++kt) {
        int cur = kt & 1;
        ushort_t* Ac = &As[cur][0];
        ushort_t* Bc = &Bs[cur][0];

        if (kt < 31) {
            // stage B kt+1 -> other buffer (async, drains at end-of-iter barrier)
            const ushort_t* bs = bsrc + (size_t)(kt + 1) * 16384;
            #pragma unroll
            for (int j = 0; j < 8; ++j)
                __builtin_amdgcn_global_load_lds(
                    (const __attribute__((address_space(1))) unsigned*)(bs + j * 512),
                    (__attribute__((address_space(3))) unsigned*)(&Bs[1 - cur][wave * 4096 + j * 512]),
                    16, 0, 0);
            // convert A kt+1 (regs loaded 2 iters ago, already complete)
            *(uint4*)&As[1 - cur][arow * 40 + acol] =
                pack8(areg[1 - cur][0], areg[1 - cur][1]);
        }
        if (kt < 30) {
            // load A for kt+2 into the slot just freed
            areg[cur][0] = *(const float4*)(asrc + (size_t)(kt + 2) * 32);
            areg[cur][1] = *(const float4*)(asrc + (size_t)(kt + 2) * 32 + 4);
        }

        // compute kt
        bf16x8 afr[4];
        #pragma unroll
        for (int mt = 0; mt < 4; ++mt)
            afr[mt] = *(const bf16x8*)&Ac[(mt * 16 + nl) * 40 + q * 8];
        #pragma unroll
        for (int ntl = 0; ntl < 8; ++ntl) {
            bf16x8 bfr = *(const bf16x8*)&Bc[((wave * 8 + ntl) * 64 + lane) * 8];
            #pragma unroll
            for (int mt = 0; mt < 4; ++mt)
                acc[mt][ntl] = __builtin_amdgcn_mfma_f32_16x16x32_bf16(
                    afr[mt], bfr, acc[mt][ntl], 0, 0, 0);
        }
        __syncthreads();
    }

    // Epilogue: C elem (m = mt*16 + q*4 + r, n = wave*128 + ntl*16 + nl)
    float p[16];
    #pragma unroll
    for (int i = 0; i < 16; ++i) p[i] = 0.f;
    #pragma unroll
    for (int ntl = 0; ntl < 8; ++ntl) {
        int n = wave * 128 + ntl * 16 + nl;
        float hv = hb[b * H + n];
        float vv = v[n];
        #pragma unroll
        for (int mt = 0; mt < 4; ++mt)
            #pragma unroll
            for (int r = 0; r < 4; ++r)
                p[mt * 4 + r] += vv * tanhf(acc[mt][ntl][r] + hv);
    }
    #pragma unroll
    for (int off = 1; off < 16; off <<= 1) {
        #pragma unroll
        for (int i = 0; i < 16; ++i) p[i] += __shfl_xor(p[i], off, 64);
    }
    if (nl == 0) {
        #pragma unroll
        for (int mt = 0; mt < 4; ++mt)
            #pragma unroll
            for (int r = 0; r < 4; ++r)
                sred[wave][mt * 16 + q * 4 + r] = p[mt * 4 + r];
    }
    __syncthreads();
    if (tid < 64) {
        float s = sred[0][tid] + sred[1][tid] + sred[2][tid] + sred[3][tid];
        scores[(size_t)b * S + s0 + tid] = s;
    }
}

// softmax over S per b; writes attention weights to out[B*E + ...] and zeros context region
__global__ void softmax_kernel(const float* __restrict__ scores, float* __restrict__ out) {
    int b = blockIdx.x, tid = threadIdx.x;
    const float* row = scores + (size_t)b * S;
    float loc[8];
    float mx = -3.4e38f;
    #pragma unroll
    for (int i = 0; i < 8; ++i) { loc[i] = row[tid + i * 256]; mx = fmaxf(mx, loc[i]); }
    #pragma unroll
    for (int off = 32; off > 0; off >>= 1) mx = fmaxf(mx, __shfl_xor(mx, off, 64));
    __shared__ float wm[4], wsm[4];
    if ((tid & 63) == 0) wm[tid >> 6] = mx;
    __syncthreads();
    mx = fmaxf(fmaxf(wm[0], wm[1]), fmaxf(wm[2], wm[3]));
    float sum = 0.f;
    #pragma unroll
    for (int i = 0; i < 8; ++i) { loc[i] = __expf(loc[i] - mx); sum += loc[i]; }
    #pragma unroll
    for (int off = 32; off > 0; off >>= 1) sum += __shfl_xor(sum, off, 64);
    if ((tid & 63) == 0) wsm[tid >> 6] = sum;
    __syncthreads();
    sum = wsm[0] + wsm[1] + wsm[2] + wsm[3];
    float inv = 1.f / sum;
    #pragma unroll
    for (int i = 0; i < 8; ++i) out[B * E + (size_t)b * S + tid + i * 256] = loc[i] * inv;
    #pragma unroll
    for (int i = 0; i < 4; ++i) out[(size_t)b * E + tid + i * 256] = 0.f;   // zero context for atomics
}

// context[b][e] = sum_s w[b][s] * enc[b][s][e]; float4 per thread (full E per block)
__global__ void context_kernel(const float* __restrict__ enc, const float* __restrict__ w_attn,
                               float* __restrict__ out_ctx) {
    int sc = blockIdx.x, b = blockIdx.y;
    int e = threadIdx.x * 4;
    const float* w  = w_attn + (size_t)b * S + sc * 128;
    const float* ep = enc + ((size_t)b * S + sc * 128) * E + e;
    float a0 = 0.f, a1 = 0.f, a2 = 0.f, a3 = 0.f;
    #pragma unroll 4
    for (int s = 0; s < 128; ++s) {
        float ws = w[s];
        float4 x = *(const float4*)(ep + (size_t)s * E);
        a0 += ws * x.x; a1 += ws * x.y; a2 += ws * x.z; a3 += ws * x.w;
    }
    float* dst = &out_ctx[(size_t)b * E + e];
    atomicAdd(dst + 0, a0);
    atomicAdd(dst + 1, a1);
    atomicAdd(dst + 2, a2);
    atomicAdd(dst + 3, a3);
}

extern "C" void kernel_launch(void* const* d_in, const int* in_sizes, int n_in,
                              void* d_out, int out_size, void* d_ws, size_t ws_size,
                              hipStream_t stream) {
    const float* hidden = (const float*)d_in[0];
    const float* enc    = (const float*)d_in[1];
    const float* Wa     = (const float*)d_in[2];
    const float* ba     = (const float*)d_in[3];
    const float* v      = (const float*)d_in[4];
    float* out = (float*)d_out;

    char* ws = (char*)d_ws;
    ushort_t* wef = (ushort_t*)ws;                        // 1 MiB  (bf16 We fragments)
    float* hb     = (float*)(ws + (1 << 20));             // 64 KiB
    float* scores = (float*)(ws + (1 << 20) + (1 << 16)); // 256 KiB

    hipMemsetAsync(hb, 0, B * H * sizeof(float), stream);
    prep_hb<<<dim3(B, 8), 256, 0, stream>>>(hidden, Wa, ba, hb);
    prep_wef<<<256, 256, 0, stream>>>(Wa, wef);
    score_kernel<<<dim3(S / 64, B), 256, 0, stream>>>(enc, wef, hb, v, scores);
    softmax_kernel<<<B, 256, 0, stream>>>(scores, out);
    context_kernel<<<dim3(16, B), 256, 0, stream>>>(enc, out + B * E, out);
}

// Round 4
// 499.551 us; speedup vs baseline: 1.1157x; 1.1157x over previous
//
#include <hip/hip_runtime.h>

typedef unsigned short ushort_t;
typedef __attribute__((ext_vector_type(8))) short bf16x8;   // 8 bf16 in 4 VGPRs
typedef __attribute__((ext_vector_type(4))) float f32x4;

#define H 512
#define E 1024
#define S 2048
#define B 32

__device__ __forceinline__ ushort_t f2bf(float f) {
    unsigned u = __float_as_uint(f);
    unsigned r = (u + 0x7FFFu + ((u >> 16) & 1u)) >> 16;   // RNE
    return (ushort_t)r;
}

// round-half-up bf16 pack of two floats: low = bf(x), high = bf(y). 3 VALU ops.
__device__ __forceinline__ unsigned pkbf(float x, float y) {
    unsigned u0 = __float_as_uint(x) + 0x8000u;
    unsigned u1 = __float_as_uint(y) + 0x8000u;
    return __builtin_amdgcn_perm(u1, u0, 0x07060302u);   // bytes [u1.3,u1.2,u0.3,u0.2]
}

// hb[b][h] = hidden[b] @ Wh + ba  — split-K over 8 chunks, atomicAdd into zeroed hb
__global__ void prep_hb(const float* __restrict__ hidden, const float* __restrict__ Wa,
                        const float* __restrict__ ba, float* __restrict__ hb) {
    int b = blockIdx.x, kc = blockIdx.y, tid = threadIdx.x;
    const float* hp = hidden + b * H + kc * 64;
    float a0 = 0.f, a1 = 0.f;
    #pragma unroll 8
    for (int k = 0; k < 64; ++k) {
        float hv = hp[k];
        a0 += hv * Wa[(size_t)(kc * 64 + k) * H + tid];
        a1 += hv * Wa[(size_t)(kc * 64 + k) * H + tid + 256];
    }
    if (kc == 0) { a0 += ba[tid]; a1 += ba[tid + 256]; }
    atomicAdd(&hb[b * H + tid], a0);
    atomicAdd(&hb[b * H + tid + 256], a1);
}

// Swizzle We (= Wa[512:]) into bf16 MFMA-B-fragment order:
// wef[((kt*32+nt)*64 + lane)*8 + j] = We[kt*32 + (lane>>4)*8 + j][nt*16 + (lane&15)]
__global__ void prep_wef(const float* __restrict__ Wa, ushort_t* __restrict__ wef) {
    int g = blockIdx.x * 256 + threadIdx.x;      // 0..65535
    int kt = g >> 11, nt = (g >> 6) & 31, l = g & 63;
    int kbase = kt * 32 + ((l >> 4) << 3);
    int n = nt * 16 + (l & 15);
    #pragma unroll
    for (int j = 0; j < 8; ++j)
        wef[(size_t)g * 8 + j] = f2bf(Wa[(size_t)(H + kbase + j) * H + n]);
}

// Fused: scores[b][s] = v . tanh( enc[b,s,:] @ We + hb[b,:] )
// 256 thr / 4 waves; tile M=64 x N=512; K-step 32, double-buffered.
// B (fragment-ordered wef) and A (fp32, xor-swizzled) both staged via
// global_load_lds; A converted to bf16 at fragment-load time (3-op pack).
__launch_bounds__(256, 2)
__global__ void score_kernel(const float* __restrict__ enc, const ushort_t* __restrict__ wef,
                             const float* __restrict__ hb, const float* __restrict__ v,
                             float* __restrict__ scores) {
    int b = blockIdx.y;
    int s0 = blockIdx.x * 64;
    int tid = threadIdx.x;
    int wave = tid >> 6, lane = tid & 63;
    int q = lane >> 4, nl = lane & 15;

    __shared__ char arena[81920];          // [0,64K): Bs[2][32K]; [64K,80K): As[2][8K]
    float* sred = (float*)arena;           // aliased after the K-loop

    f32x4 acc[4][8] = {};

    // ---- staging source pointers (per lane) ----
    // B: identity layout; wave covers bytes [wave*8192, +8192) of each 32KB slice
    const char* bsrc = (const char*)wef + wave * 8192 + lane * 16;
    // A: slot i = wave*128 + j*64 + lane holds row r = wave*16+j*8+(lane>>3),
    //    chunk c = (lane&7)^(lane>>3)  (xor swizzle; slot = r*8 + (c^(r&7)))
    int r0 = wave * 16 + (lane >> 3);
    int c4 = ((lane & 7) ^ (lane >> 3)) * 4;
    const float* asrc0 = enc + ((size_t)b * S + s0 + r0) * E + c4;
    const float* asrc1 = asrc0 + 8 * E;

#define STAGE(KT, D)                                                                     \
    {                                                                                    \
        const char* bp = bsrc + (size_t)(KT) * 32768;                                    \
        char* bl = arena + (D) * 32768 + wave * 8192;                                    \
        _Pragma("unroll")                                                                \
        for (int j = 0; j < 8; ++j)                                                      \
            __builtin_amdgcn_global_load_lds(                                            \
                (const __attribute__((address_space(1))) unsigned*)(bp + j * 1024),      \
                (__attribute__((address_space(3))) unsigned*)(bl + j * 1024), 16, 0, 0); \
        char* al = arena + 65536 + (D) * 8192 + wave * 2048;                             \
        __builtin_amdgcn_global_load_lds(                                                \
            (const __attribute__((address_space(1))) unsigned*)(asrc0 + (KT) * 32),      \
            (__attribute__((address_space(3))) unsigned*)(al), 16, 0, 0);                \
        __builtin_amdgcn_global_load_lds(                                                \
            (const __attribute__((address_space(1))) unsigned*)(asrc1 + (KT) * 32),      \
            (__attribute__((address_space(3))) unsigned*)(al + 1024), 16, 0, 0);         \
    }

#define COMPUTE(CUR)                                                                     \
    {                                                                                    \
        const ushort_t* Bc = (const ushort_t*)(arena + (CUR) * 32768);                   \
        const float*    Ac = (const float*)(arena + 65536 + (CUR) * 8192);               \
        bf16x8 afr[4];                                                                   \
        _Pragma("unroll")                                                                \
        for (int mt = 0; mt < 4; ++mt) {                                                 \
            int r = mt * 16 + nl;                                                        \
            int sa = r * 8 + ((2 * q) ^ (nl & 7));                                       \
            int sb = r * 8 + ((2 * q + 1) ^ (nl & 7));                                   \
            float4 f0 = *(const float4*)(Ac + sa * 4);                                   \
            float4 f1 = *(const float4*)(Ac + sb * 4);                                   \
            uint4 u;                                                                     \
            u.x = pkbf(f0.x, f0.y); u.y = pkbf(f0.z, f0.w);                              \
            u.z = pkbf(f1.x, f1.y); u.w = pkbf(f1.z, f1.w);                              \
            afr[mt] = *(bf16x8*)&u;                                                      \
        }                                                                                \
        _Pragma("unroll")                                                                \
        for (int ntl = 0; ntl < 8; ++ntl) {                                              \
            bf16x8 bfr = *(const bf16x8*)&Bc[((wave * 8 + ntl) * 64 + lane) * 8];        \
            _Pragma("unroll")                                                            \
            for (int mt = 0; mt < 4; ++mt)                                               \
                acc[mt][ntl] = __builtin_amdgcn_mfma_f32_16x16x32_bf16(                  \
                    afr[mt], bfr, acc[mt][ntl], 0, 0, 0);                                \
        }                                                                                \
    }

    STAGE(0, 0);
    __syncthreads();                        // drains vmcnt(0): buffer 0 ready
    for (int kt = 0; kt < 31; ++kt) {
        STAGE(kt + 1, (kt + 1) & 1);        // async into other buffer
        COMPUTE(kt & 1);                    // ds_read + MFMA on current buffer
        __syncthreads();                    // staging landed during compute
    }
    COMPUTE(1);
    __syncthreads();                        // all LDS reads done before arena reuse

    // Epilogue: C elem (m = mt*16 + q*4 + r, n = wave*128 + ntl*16 + nl)
    float p[16];
    #pragma unroll
    for (int i = 0; i < 16; ++i) p[i] = 0.f;
    #pragma unroll
    for (int ntl = 0; ntl < 8; ++ntl) {
        int n = wave * 128 + ntl * 16 + nl;
        float hv = hb[b * H + n];
        float vv = v[n];
        #pragma unroll
        for (int mt = 0; mt < 4; ++mt)
            #pragma unroll
            for (int r = 0; r < 4; ++r)
                p[mt * 4 + r] += vv * tanhf(acc[mt][ntl][r] + hv);
    }
    #pragma unroll
    for (int off = 1; off < 16; off <<= 1) {
        #pragma unroll
        for (int i = 0; i < 16; ++i) p[i] += __shfl_xor(p[i], off, 64);
    }
    if (nl == 0) {
        #pragma unroll
        for (int mt = 0; mt < 4; ++mt)
            #pragma unroll
            for (int r = 0; r < 4; ++r)
                sred[wave * 64 + mt * 16 + q * 4 + r] = p[mt * 4 + r];
    }
    __syncthreads();
    if (tid < 64) {
        float s = sred[tid] + sred[64 + tid] + sred[128 + tid] + sred[192 + tid];
        scores[(size_t)b * S + s0 + tid] = s;
    }
#undef STAGE
#undef COMPUTE
}

// softmax over S per b; writes attention weights to out[B*E + ...] and zeros context region
__global__ void softmax_kernel(const float* __restrict__ scores, float* __restrict__ out) {
    int b = blockIdx.x, tid = threadIdx.x;
    const float* row = scores + (size_t)b * S;
    float loc[8];
    float mx = -3.4e38f;
    #pragma unroll
    for (int i = 0; i < 8; ++i) { loc[i] = row[tid + i * 256]; mx = fmaxf(mx, loc[i]); }
    #pragma unroll
    for (int off = 32; off > 0; off >>= 1) mx = fmaxf(mx, __shfl_xor(mx, off, 64));
    __shared__ float wm[4], wsm[4];
    if ((tid & 63) == 0) wm[tid >> 6] = mx;
    __syncthreads();
    mx = fmaxf(fmaxf(wm[0], wm[1]), fmaxf(wm[2], wm[3]));
    float sum = 0.f;
    #pragma unroll
    for (int i = 0; i < 8; ++i) { loc[i] = __expf(loc[i] - mx); sum += loc[i]; }
    #pragma unroll
    for (int off = 32; off > 0; off >>= 1) sum += __shfl_xor(sum, off, 64);
    if ((tid & 63) == 0) wsm[tid >> 6] = sum;
    __syncthreads();
    sum = wsm[0] + wsm[1] + wsm[2] + wsm[3];
    float inv = 1.f / sum;
    #pragma unroll
    for (int i = 0; i < 8; ++i) out[B * E + (size_t)b * S + tid + i * 256] = loc[i] * inv;
    #pragma unroll
    for (int i = 0; i < 4; ++i) out[(size_t)b * E + tid + i * 256] = 0.f;   // zero context for atomics
}

// context[b][e] = sum_s w[b][s] * enc[b][s][e]; 64 s-rows per block, float4/thread
__global__ void context_kernel(const float* __restrict__ enc, const float* __restrict__ w_attn,
                               float* __restrict__ out_ctx) {
    int sc = blockIdx.x, b = blockIdx.y;
    int e = threadIdx.x * 4;
    const float* w  = w_attn + (size_t)b * S + sc * 64;
    const float* ep = enc + ((size_t)b * S + sc * 64) * E + e;
    float a0 = 0.f, a1 = 0.f, a2 = 0.f, a3 = 0.f;
    #pragma unroll 8
    for (int s = 0; s < 64; ++s) {
        float ws = w[s];
        float4 x = *(const float4*)(ep + (size_t)s * E);
        a0 += ws * x.x; a1 += ws * x.y; a2 += ws * x.z; a3 += ws * x.w;
    }
    float* dst = &out_ctx[(size_t)b * E + e];
    atomicAdd(dst + 0, a0);
    atomicAdd(dst + 1, a1);
    atomicAdd(dst + 2, a2);
    atomicAdd(dst + 3, a3);
}

extern "C" void kernel_launch(void* const* d_in, const int* in_sizes, int n_in,
                              void* d_out, int out_size, void* d_ws, size_t ws_size,
                              hipStream_t stream) {
    const float* hidden = (const float*)d_in[0];
    const float* enc    = (const float*)d_in[1];
    const float* Wa     = (const float*)d_in[2];
    const float* ba     = (const float*)d_in[3];
    const float* v      = (const float*)d_in[4];
    float* out = (float*)d_out;

    char* ws = (char*)d_ws;
    ushort_t* wef = (ushort_t*)ws;                        // 1 MiB  (bf16 We fragments)
    float* hb     = (float*)(ws + (1 << 20));             // 64 KiB
    float* scores = (float*)(ws + (1 << 20) + (1 << 16)); // 256 KiB

    hipMemsetAsync(hb, 0, B * H * sizeof(float), stream);
    prep_hb<<<dim3(B, 8), 256, 0, stream>>>(hidden, Wa, ba, hb);
    prep_wef<<<256, 256, 0, stream>>>(Wa, wef);
    score_kernel<<<dim3(S / 64, B), 256, 0, stream>>>(enc, wef, hb, v, scores);
    softmax_kernel<<<B, 256, 0, stream>>>(scores, out);
    context_kernel<<<dim3(32, B), 256, 0, stream>>>(enc, out + B * E, out);
}